// Round 4
// baseline (24615.018 us; speedup 1.0000x reference)
//
#include <hip/hip_runtime.h>
#include <hip/hip_bf16.h>

namespace {
constexpr int B  = 64;
constexpr int T  = 2048;
constexpr int L  = 200;
constexpr int H  = 256;
constexpr int KV = 256;
constexpr int E  = 256;
constexpr int V  = 33;
constexpr int MH = 512;
constexpr int G  = 4 * H;
constexpr int HB = H * B;

// ---- new-path workspace layout (bytes; h2v elem = 4 B) ----
constexpr size_t P_XEH  = 0;                                  // [L][B][128] h2v
constexpr size_t P_KF   = P_XEH + (size_t)L * B * 128 * 4;    // [B][T][128] h2v
constexpr size_t P_VF   = P_KF  + (size_t)B * T * 128 * 4;
constexpr size_t P_WIH0 = P_VF  + (size_t)B * T * 128 * 4;    // [256][1024] h2v
constexpr size_t P_WHH0 = P_WIH0 + (size_t)256 * 1024 * 4;    // [128][1024]
constexpr size_t P_WIR1 = P_WHH0 + (size_t)128 * 1024 * 4;
constexpr size_t P_WHH1 = P_WIR1 + (size_t)128 * 1024 * 4;
constexpr size_t P_WIR2 = P_WHH1 + (size_t)128 * 1024 * 4;
constexpr size_t P_WHH2 = P_WIR2 + (size_t)128 * 1024 * 4;
constexpr size_t P_FC1T = P_WHH2 + (size_t)128 * 1024 * 4;    // [256][512]
constexpr size_t P_FC2H = P_FC1T + (size_t)256 * 512 * 4;     // [33][256]
constexpr size_t P_BSUM = P_FC2H + (size_t)33 * 256 * 4;      // [3][1024] f32
constexpr size_t P_END  = P_BSUM + (size_t)3 * 1024 * 4;      // ~141.7 MB

// ---- legacy (round-0 fp32) layout in floats ----
constexpr long OFF_H   = 0;
constexpr long OFF_C   = OFF_H  + 2L * 3 * HB;
constexpr long OFF_CTX = OFF_C  + 3L * HB;
constexpr long OFF_Z   = OFF_CTX + 2L * KV * B;
constexpr long OFF_M   = OFF_Z  + 2L * B;
constexpr long OFF_E   = OFF_M  + B;
constexpr long OFF_HID = OFF_E  + (long)B * T;
constexpr long OFF_XE  = OFF_HID + (long)MH * B;
constexpr long FLOATS_LEG = OFF_XE + (long)L * E * B;
constexpr long NEED_LEG = FLOATS_LEG * 4;
}

typedef _Float16 h2v __attribute__((ext_vector_type(2)));

__device__ __forceinline__ float dot2(h2v a, h2v b, float c) {
#if __has_builtin(__builtin_amdgcn_fdot2)
  return __builtin_amdgcn_fdot2(a, b, c, false);
#else
  return c + (float)a.x * (float)b.x + (float)a.y * (float)b.y;
#endif
}
__device__ __forceinline__ h2v packh2(float a, float b) {
  h2v r; r.x = (_Float16)a; r.y = (_Float16)b; return r;
}
__device__ __forceinline__ float sigm(float x) { return 1.f / (1.f + __expf(-x)); }
__device__ __forceinline__ float tanh_f(float x) {
  float xc = fminf(fmaxf(x, -15.f), 15.f);
  float e2 = __expf(2.f * xc);
  return (e2 - 1.f) / (e2 + 1.f);
}
__device__ __forceinline__ void atomicMaxFloat(float* p, float v) {
  int old = __float_as_int(*p);
  while (__int_as_float(old) < v) {
    int assumed = old;
    old = atomicCAS((int*)p, assumed, __float_as_int(v));
    if (old == assumed) break;
  }
}

// ================= new path =================

// one-time: embed (f16 pairs) + weight transpose/convert + bias sums
__global__ __launch_bounds__(256) void k_prep(
    const int* __restrict__ labels, const float* __restrict__ emb,
    const float* __restrict__ w_ih0, const float* __restrict__ w_hh0,
    const float* __restrict__ b_ih0, const float* __restrict__ b_hh0,
    const float* __restrict__ w_ihr, const float* __restrict__ w_hhr,
    const float* __restrict__ b_ihr, const float* __restrict__ b_hhr,
    const float* __restrict__ fc1_w, const float* __restrict__ fc2_w,
    h2v* __restrict__ xeh, h2v* __restrict__ wih0t, h2v* __restrict__ whh0t,
    h2v* __restrict__ wir1t, h2v* __restrict__ whh1t,
    h2v* __restrict__ wir2t, h2v* __restrict__ whh2t,
    h2v* __restrict__ fc1t, h2v* __restrict__ fc2h, float* __restrict__ bsum) {
  int blk = blockIdx.x, tid = threadIdx.x;
  if (blk < 6400) {                      // xeh: i = ((t*64+b)*128)+p
    int i = blk * 256 + tid;
    int p = i & 127, b = (i >> 7) & 63, t = i >> 13;
    int lab = labels[t * 64 + b];
    xeh[i] = packh2(emb[lab * 256 + 2 * p], emb[lab * 256 + 2 * p + 1]);
  } else if (blk < 7424) {               // wih0t [kk<256][j<1024], src pitch 512
    int i = (blk - 6400) * 256 + tid;
    int j = i & 1023, kk = i >> 10;
    wih0t[i] = packh2(w_ih0[j * 512 + 2 * kk], w_ih0[j * 512 + 2 * kk + 1]);
  } else if (blk < 7936) {               // whh0t [kk<128][j], src pitch 256
    int i = (blk - 7424) * 256 + tid;
    int j = i & 1023, kk = i >> 10;
    whh0t[i] = packh2(w_hh0[j * 256 + 2 * kk], w_hh0[j * 256 + 2 * kk + 1]);
  } else if (blk < 8448) {               // wir1t
    int i = (blk - 7936) * 256 + tid;
    int j = i & 1023, kk = i >> 10;
    wir1t[i] = packh2(w_ihr[j * 256 + 2 * kk], w_ihr[j * 256 + 2 * kk + 1]);
  } else if (blk < 8960) {               // whh1t
    int i = (blk - 8448) * 256 + tid;
    int j = i & 1023, kk = i >> 10;
    whh1t[i] = packh2(w_hhr[j * 256 + 2 * kk], w_hhr[j * 256 + 2 * kk + 1]);
  } else if (blk < 9472) {               // wir2t (layer 2 = offset 1024*256)
    int i = (blk - 8960) * 256 + tid;
    int j = i & 1023, kk = i >> 10;
    const float* s = w_ihr + 1024 * 256;
    wir2t[i] = packh2(s[j * 256 + 2 * kk], s[j * 256 + 2 * kk + 1]);
  } else if (blk < 9984) {               // whh2t
    int i = (blk - 9472) * 256 + tid;
    int j = i & 1023, kk = i >> 10;
    const float* s = w_hhr + 1024 * 256;
    whh2t[i] = packh2(s[j * 256 + 2 * kk], s[j * 256 + 2 * kk + 1]);
  } else if (blk < 10496) {              // fc1t [kk<256][j<512], src pitch 512
    int i = (blk - 9984) * 256 + tid;
    int j = i & 511, kk = i >> 9;
    fc1t[i] = packh2(fc1_w[j * 512 + 2 * kk], fc1_w[j * 512 + 2 * kk + 1]);
  } else if (blk < 10529) {              // fc2h [v<33][kk<256], row-major pairs
    int i = (blk - 10496) * 256 + tid;
    if (i < 33 * 256) {
      int v = i >> 8, kk = i & 255;
      fc2h[i] = packh2(fc2_w[v * 512 + 2 * kk], fc2_w[v * 512 + 2 * kk + 1]);
    }
  } else {                               // bsum [l<3][j<1024]
    int i = (blk - 10529) * 256 + tid;
    if (i < 3 * 1024) {
      int l = i >> 10, j = i & 1023;
      float s = (l == 0) ? (b_ih0[j] + b_hh0[j])
                         : (b_ihr[(l - 1) * 1024 + j] + b_hhr[(l - 1) * 1024 + j]);
      bsum[i] = s;
    }
  }
}

__global__ __launch_bounds__(256) void k_cvtKV(
    const float2* __restrict__ k32, const float2* __restrict__ v32,
    h2v* __restrict__ k16, h2v* __restrict__ v16, int npairs) {
  int stride = gridDim.x * blockDim.x;
  for (int i = blockIdx.x * blockDim.x + threadIdx.x; i < npairs; i += stride) {
    float2 a = k32[i]; k16[i] = packh2(a.x, a.y);
    float2 b = v32[i]; v16[i] = packh2(b.x, b.y);
  }
}

// the whole 200-step recurrence: one workgroup per batch element, state in LDS
__global__ __launch_bounds__(1024) void k_seq(
    const h2v* __restrict__ xeh, const h2v* __restrict__ kf, const h2v* __restrict__ vf,
    const int* __restrict__ lens,
    const h2v* __restrict__ wih0t, const h2v* __restrict__ whh0t,
    const h2v* __restrict__ wir1t, const h2v* __restrict__ whh1t,
    const h2v* __restrict__ wir2t, const h2v* __restrict__ whh2t,
    const float* __restrict__ bsum,
    const h2v* __restrict__ fc1t, const float* __restrict__ fc1_b,
    const h2v* __restrict__ fc2h, const float* __restrict__ fc2_b,
    float* __restrict__ out) {
  const int b = blockIdx.x, tid = threadIdx.x;
  const int lane = tid & 63, wv = tid >> 6;
  const int len = lens[b];

  __shared__ h2v hh[3][128];      // h per layer, f16 pairs
  __shared__ h2v xh[128];         // x(t) pairs
  __shared__ h2v cxh[256];        // [0..127]=h2(t) pairs, [128..255]=ctx(t+1)*1/Z pairs
  __shared__ h2v hid2[256];       // fc1 output pairs
  __shared__ float c32[3 * 256];  // cell states fp32
  __shared__ float g[1024];       // gate / staging
  __shared__ float ctxacc[258];   // [0..255]=ctx accum, [256]=Z

  {
    h2v z2 = packh2(0.f, 0.f);
    if (tid < 128) { hh[0][tid] = z2; hh[1][tid] = z2; hh[2][tid] = z2; cxh[128 + tid] = z2; }
    if (tid < 256) { c32[tid] = 0.f; c32[256 + tid] = 0.f; c32[512 + tid] = 0.f; }
  }
  const h2v* kb = kf + (size_t)b * T * 128;
  const h2v* vb = vf + (size_t)b * T * 128;

  for (int t = 0; t < L; ++t) {
    if (tid < 128) xh[tid] = xeh[((size_t)t * 64 + b) * 128 + tid];
    __syncthreads();

    // ---- cell0 (row j = tid; input = [x | ctx*1/Z], rec = h0) ----
    {
      float acc = bsum[tid];
      const h2v* w  = wih0t + tid;
      const h2v* wh = whh0t + tid;
      #pragma unroll 8
      for (int kk = 0; kk < 128; ++kk) acc = dot2(w[kk * 1024], xh[kk], acc);
      #pragma unroll 8
      for (int kk = 128; kk < 256; ++kk) acc = dot2(w[kk * 1024], cxh[kk], acc);
      #pragma unroll 8
      for (int kk = 0; kk < 128; ++kk) acc = dot2(wh[kk * 1024], hh[0][kk], acc);
      g[tid] = acc;
    }
    __syncthreads();
    if (tid < 256) {
      float c = sigm(g[256 + tid]) * c32[tid] + sigm(g[tid]) * tanh_f(g[512 + tid]);
      float h = sigm(g[768 + tid]) * tanh_f(c);
      c32[tid] = c; g[tid] = h;
    }
    __syncthreads();
    if (tid < 128) hh[0][tid] = packh2(g[2 * tid], g[2 * tid + 1]);
    __syncthreads();

    // ---- cell1 ----
    {
      float acc = bsum[1024 + tid];
      const h2v* w  = wir1t + tid;
      const h2v* wh = whh1t + tid;
      #pragma unroll 8
      for (int kk = 0; kk < 128; ++kk) acc = dot2(w[kk * 1024], hh[0][kk], acc);
      #pragma unroll 8
      for (int kk = 0; kk < 128; ++kk) acc = dot2(wh[kk * 1024], hh[1][kk], acc);
      g[tid] = acc;
    }
    __syncthreads();
    if (tid < 256) {
      float c = sigm(g[256 + tid]) * c32[256 + tid] + sigm(g[tid]) * tanh_f(g[512 + tid]);
      float h = sigm(g[768 + tid]) * tanh_f(c);
      c32[256 + tid] = c; g[tid] = h;
    }
    __syncthreads();
    if (tid < 128) hh[1][tid] = packh2(g[2 * tid], g[2 * tid + 1]);
    __syncthreads();

    // ---- cell2 ----
    {
      float acc = bsum[2048 + tid];
      const h2v* w  = wir2t + tid;
      const h2v* wh = whh2t + tid;
      #pragma unroll 8
      for (int kk = 0; kk < 128; ++kk) acc = dot2(w[kk * 1024], hh[1][kk], acc);
      #pragma unroll 8
      for (int kk = 0; kk < 128; ++kk) acc = dot2(wh[kk * 1024], hh[2][kk], acc);
      g[tid] = acc;
    }
    __syncthreads();
    if (tid < 256) {
      float c = sigm(g[256 + tid]) * c32[512 + tid] + sigm(g[tid]) * tanh_f(g[512 + tid]);
      float h = sigm(g[768 + tid]) * tanh_f(c);
      c32[512 + tid] = c; g[tid] = h;
    }
    if (tid >= 256 && tid < 514) ctxacc[tid - 256] = 0.f;   // zero attn accumulators
    if (tid == 514) { }
    __syncthreads();
    if (tid < 128) { h2v p = packh2(g[2 * tid], g[2 * tid + 1]); hh[2][tid] = p; cxh[tid] = p; }
    __syncthreads();

    // ---- fused attention (rows strided over 16 waves; clamped exp, no max pass) ----
    {
      const int i0 = 2 * lane, i1 = 2 * lane + 1;
      h2v q0 = hh[2][i0], q1 = hh[2][i1];
      float a0 = 0.f, a1 = 0.f, a2 = 0.f, a3 = 0.f, zp = 0.f;
      for (int r = wv; r < len; r += 16) {
        const h2v* kr = kb + (size_t)r * 128;
        const h2v* vr = vb + (size_t)r * 128;
        float e = dot2(kr[i0], q0, 0.f);
        e = dot2(kr[i1], q1, e);
        #pragma unroll
        for (int o = 32; o; o >>= 1) e += __shfl_xor(e, o, 64);
        float w = __expf(fminf(e, 50.f));
        float vx0 = (float)vr[i0].x, vy0 = (float)vr[i0].y;
        float vx1 = (float)vr[i1].x, vy1 = (float)vr[i1].y;
        a0 += w * vx0; a1 += w * vy0; a2 += w * vx1; a3 += w * vy1;
        zp += w;
      }
      atomicAdd(&ctxacc[4 * lane + 0], a0);
      atomicAdd(&ctxacc[4 * lane + 1], a1);
      atomicAdd(&ctxacc[4 * lane + 2], a2);
      atomicAdd(&ctxacc[4 * lane + 3], a3);
      if (lane == 0) atomicAdd(&ctxacc[256], zp);
    }
    __syncthreads();
    if (tid < 128) {
      float zz = 1.f / fmaxf(ctxacc[256], 1e-12f);
      cxh[128 + tid] = packh2(ctxacc[2 * tid] * zz, ctxacc[2 * tid + 1] * zz);
    }
    __syncthreads();

    // ---- fc1 (512 rows; input pairs = cxh) ----
    if (tid < 512) {
      float acc = fc1_b[tid];
      const h2v* w = fc1t + tid;
      #pragma unroll 8
      for (int kk = 0; kk < 256; ++kk) acc = dot2(w[kk * 512], cxh[kk], acc);
      g[tid] = fmaxf(acc, 0.f);
    }
    __syncthreads();
    if (tid < 256) hid2[tid] = packh2(g[2 * tid], g[2 * tid + 1]);
    __syncthreads();

    // ---- fc2 (33 rows over waves; lane-parallel dot) ----
    for (int v = wv; v < 33; v += 16) {
      const h2v* wr = fc2h + v * 256 + 4 * lane;
      float acc = dot2(wr[0], hid2[4 * lane + 0], 0.f);
      acc = dot2(wr[1], hid2[4 * lane + 1], acc);
      acc = dot2(wr[2], hid2[4 * lane + 2], acc);
      acc = dot2(wr[3], hid2[4 * lane + 3], acc);
      #pragma unroll
      for (int o = 32; o; o >>= 1) acc += __shfl_xor(acc, o, 64);
      if (lane == 0) out[((size_t)b * L + t) * V + v] = acc + fc2_b[v];
    }
    __syncthreads();
  }
}

// ================= legacy fp32 fallback (round-0, validated) =================

__global__ void k_init(float* __restrict__ ws) {
  int i = blockIdx.x * blockDim.x + threadIdx.x;
  if (i < 3 * HB) { ws[OFF_H + i] = 0.f; ws[OFF_C + i] = 0.f; }
  if (i < KV * B) ws[OFF_CTX + i] = 0.f;
  if (i < B)      ws[OFF_Z + i] = 1.f;
}

__global__ void k_embed(const int* __restrict__ labels, const float* __restrict__ emb,
                        float* __restrict__ xembT) {
  int i = blockIdx.x * blockDim.x + threadIdx.x;
  if (i >= L * E * B) return;
  int b = i & 63, e = (i >> 6) & 255, l = i >> 14;
  int lab = labels[l * B + b];
  xembT[i] = emb[lab * E + e];
}

__global__ __launch_bounds__(512) void k_cell0(
    const float* __restrict__ wih, const float* __restrict__ whh,
    const float* __restrict__ bih, const float* __restrict__ bhh,
    const float* __restrict__ xe,
    const float* __restrict__ ctx, const float* __restrict__ Z,
    const float* __restrict__ hprev,
    float* __restrict__ hnew, float* __restrict__ cst) {
  int t = threadIdx.x;
  int b = t & 63, q = (t >> 6) & 3, ks = t >> 8;
  int j = blockIdx.x;
  int row = q * H + j;
  float acc = 0.f, s0 = 0.f, s1 = 0.f, a2 = 0.f;
  if (ks == 0) {
    acc = bih[row] + bhh[row];
    const float* wi = wih + (long)row * (E + KV);
    for (int k = 0; k < E; k += 2) {
      s0 += wi[k]   * xe[(k)   * B + b];
      s1 += wi[k+1] * xe[(k+1) * B + b];
    }
    const float* wh = whh + (long)row * H;
    for (int k = 0; k < 128; ++k) a2 += wh[k] * hprev[k * B + b];
    acc += s0 + s1 + a2;
  } else {
    float zz = 1.f / fmaxf(Z[b], 1e-12f);
    const float* wi = wih + (long)row * (E + KV) + E;
    for (int k = 0; k < KV; k += 2) {
      s0 += wi[k]   * ctx[(k)   * B + b];
      s1 += wi[k+1] * ctx[(k+1) * B + b];
    }
    const float* wh = whh + (long)row * H + 128;
    for (int k = 0; k < 128; ++k) a2 += wh[k] * hprev[(128 + k) * B + b];
    acc = (s0 + s1) * zz + a2;
  }
  __shared__ float sh[2][4][64];
  sh[ks][q][b] = acc;
  __syncthreads();
  if (t < 64) {
    float gi = sh[0][0][t] + sh[1][0][t];
    float gf = sh[0][1][t] + sh[1][1][t];
    float gg = sh[0][2][t] + sh[1][2][t];
    float go = sh[0][3][t] + sh[1][3][t];
    float c = sigm(gf) * cst[j * B + t] + sigm(gi) * tanh_f(gg);
    float h = sigm(go) * tanh_f(c);
    cst[j * B + t] = c;
    hnew[j * B + t] = h;
  }
}

__global__ __launch_bounds__(512) void k_cellr(
    const float* __restrict__ wih, const float* __restrict__ whh,
    const float* __restrict__ bih, const float* __restrict__ bhh,
    const float* __restrict__ hin, const float* __restrict__ hprevL,
    float* __restrict__ hnewL, float* __restrict__ cst,
    float* __restrict__ ctxn, float* __restrict__ Zn, float* __restrict__ m, int aux) {
  int t = threadIdx.x;
  int b = t & 63, q = (t >> 6) & 3, ks = t >> 8;
  int j = blockIdx.x;
  int row = q * H + j;
  if (aux) {
    int gid = blockIdx.x * 512 + t;
    if (gid < KV * B) ctxn[gid] = 0.f;
    if (gid < B) { Zn[gid] = 0.f; m[gid] = -3.4e38f; }
  }
  float acc = ks ? 0.f : (bih[row] + bhh[row]);
  float a1 = 0.f, a3 = 0.f;
  const float* wi = wih + (long)row * H + ks * 128;
  const float* wh = whh + (long)row * H + ks * 128;
  int k0 = ks * 128;
  for (int k = 0; k < 128; ++k) {
    a1 += wi[k] * hin[(k0 + k) * B + b];
    a3 += wh[k] * hprevL[(k0 + k) * B + b];
  }
  acc += a1 + a3;
  __shared__ float sh[2][4][64];
  sh[ks][q][b] = acc;
  __syncthreads();
  if (t < 64) {
    float gi = sh[0][0][t] + sh[1][0][t];
    float gf = sh[0][1][t] + sh[1][1][t];
    float gg = sh[0][2][t] + sh[1][2][t];
    float go = sh[0][3][t] + sh[1][3][t];
    float c = sigm(gf) * cst[j * B + t] + sigm(gi) * tanh_f(gg);
    float h = sigm(go) * tanh_f(c);
    cst[j * B + t] = c;
    hnewL[j * B + t] = h;
  }
}

__global__ __launch_bounds__(256) void k_energy(
    const float* __restrict__ keyp, const float* __restrict__ h2,
    const int* __restrict__ lens, float* __restrict__ e, float* __restrict__ m) {
  int b = blockIdx.y;
  int len = lens[b];
  int wave = threadIdx.x >> 6, lane = threadIdx.x & 63;
  int t0 = (blockIdx.x * 4 + wave) * 16;
  if (t0 >= len) return;
  float h0 = h2[(4 * lane + 0) * B + b];
  float h1 = h2[(4 * lane + 1) * B + b];
  float h2v_ = h2[(4 * lane + 2) * B + b];
  float h3 = h2[(4 * lane + 3) * B + b];
  int tend = min(t0 + 16, len);
  float wmax = -3.4e38f;
  for (int t = t0; t < tend; t++) {
    float4 kv = ((const float4*)(keyp + (size_t)(b * T + t) * KV))[lane];
    float s = kv.x * h0 + kv.y * h1 + kv.z * h2v_ + kv.w * h3;
    #pragma unroll
    for (int off = 32; off; off >>= 1) s += __shfl_xor(s, off, 64);
    if (lane == 0) e[b * T + t] = s;
    wmax = fmaxf(wmax, s);
  }
  if (lane == 0) atomicMaxFloat(&m[b], wmax);
}

__global__ __launch_bounds__(256) void k_pv(
    const float* __restrict__ valp, const float* __restrict__ e, const float* __restrict__ m,
    const int* __restrict__ lens, float* __restrict__ ctxn, float* __restrict__ Zn) {
  int b = blockIdx.y;
  int len = lens[b];
  int t0blk = blockIdx.x * 256;
  if (t0blk >= len) return;
  int wave = threadIdx.x >> 6, lane = threadIdx.x & 63;
  float mb = m[b];
  float a0 = 0.f, a1 = 0.f, a2 = 0.f, a3 = 0.f, zp = 0.f;
  int t0 = t0blk + wave * 64;
  int tend = min(t0 + 64, len);
  for (int t = t0; t < tend; t++) {
    float w = __expf(e[b * T + t] - mb);
    float4 vv = ((const float4*)(valp + (size_t)(b * T + t) * KV))[lane];
    a0 += w * vv.x; a1 += w * vv.y; a2 += w * vv.z; a3 += w * vv.w;
    zp += w;
  }
  __shared__ float sh[4][256];
  __shared__ float shz[4];
  sh[wave][4 * lane + 0] = a0;
  sh[wave][4 * lane + 1] = a1;
  sh[wave][4 * lane + 2] = a2;
  sh[wave][4 * lane + 3] = a3;
  if (lane == 0) shz[wave] = zp;
  __syncthreads();
  if (wave == 0) {
    #pragma unroll
    for (int r = 0; r < 4; r++) {
      int d = lane * 4 + r;
      float s = sh[0][d] + sh[1][d] + sh[2][d] + sh[3][d];
      atomicAdd(&ctxn[d * B + b], s);
    }
    if (lane == 0) atomicAdd(&Zn[b], shz[0] + shz[1] + shz[2] + shz[3]);
  }
}

__global__ __launch_bounds__(256) void k_fc1(
    const float* __restrict__ w, const float* __restrict__ bias,
    const float* __restrict__ h2, const float* __restrict__ ctxn, const float* __restrict__ Zn,
    float* __restrict__ hid) {
  int t = threadIdx.x;
  int b = t & 63, jl = t >> 6;
  int j = blockIdx.x * 4 + jl;
  float zz = 1.f / fmaxf(Zn[b], 1e-12f);
  const float* wr = w + (long)j * (H + KV);
  float s0 = 0.f, a2 = 0.f;
  for (int k = 0; k < H; ++k) s0 += wr[k] * h2[k * B + b];
  for (int k = 0; k < KV; ++k) a2 += wr[H + k] * ctxn[k * B + b];
  hid[j * B + b] = fmaxf(bias[j] + s0 + a2 * zz, 0.f);
}

__global__ __launch_bounds__(64) void k_fc2(
    const float* __restrict__ w, const float* __restrict__ bias,
    const float* __restrict__ hid, float* __restrict__ out, int step) {
  int b = threadIdx.x;
  int v = blockIdx.x;
  const float* wr = w + (long)v * MH;
  float s0 = 0.f;
  for (int k = 0; k < MH; ++k) s0 += wr[k] * hid[k * B + b];
  out[((long)b * L + step) * V + v] = bias[v] + s0;
}

static void launch_legacy(const float* key, const float* value, const int* lens,
                          const float* w_ih0, const float* w_hh0,
                          const float* b_ih0, const float* b_hh0,
                          const float* w_ihr, const float* w_hhr,
                          const float* b_ihr, const float* b_hhr,
                          const float* fc1_w, const float* fc1_b,
                          const float* fc2_w, const float* fc2_b,
                          float* out, float* ws, hipStream_t stream) {
  float* hbuf = ws + OFF_H;
  float* cbuf = ws + OFF_C;
  float* ctxb = ws + OFF_CTX;
  float* Zb   = ws + OFF_Z;
  float* mb   = ws + OFF_M;
  float* eb   = ws + OFF_E;
  float* hid  = ws + OFF_HID;
  float* xe   = ws + OFF_XE;
  for (int t = 0; t < L; t++) {
    int cur = t & 1, nxt = cur ^ 1;
    float* hprev = hbuf + (long)cur * 3 * HB;
    float* hnew  = hbuf + (long)nxt * 3 * HB;
    float* ctxc  = ctxb + (long)cur * KV * B;
    float* ctxn  = ctxb + (long)nxt * KV * B;
    float* Zc = Zb + cur * B;
    float* Zn = Zb + nxt * B;
    k_cell0<<<H, 512, 0, stream>>>(w_ih0, w_hh0, b_ih0, b_hh0,
                                   xe + (long)t * E * B, ctxc, Zc, hprev, hnew, cbuf);
    k_cellr<<<H, 512, 0, stream>>>(w_ihr, w_hhr, b_ihr, b_hhr,
                                   hnew, hprev + HB, hnew + HB, cbuf + HB,
                                   ctxn, Zn, mb, 1);
    k_cellr<<<H, 512, 0, stream>>>(w_ihr + (long)G * H, w_hhr + (long)G * H,
                                   b_ihr + G, b_hhr + G,
                                   hnew + HB, hprev + 2 * HB, hnew + 2 * HB, cbuf + 2 * HB,
                                   nullptr, nullptr, nullptr, 0);
    k_energy<<<dim3(T / 64, B), 256, 0, stream>>>(key, hnew + 2 * HB, lens, eb, mb);
    k_pv<<<dim3(T / 256, B), 256, 0, stream>>>(value, eb, mb, lens, ctxn, Zn);
    k_fc1<<<MH / 4, 256, 0, stream>>>(fc1_w, fc1_b, hnew + 2 * HB, ctxn, Zn, hid);
    k_fc2<<<V, 64, 0, stream>>>(fc2_w, fc2_b, hid, out, t);
  }
}

extern "C" void kernel_launch(void* const* d_in, const int* in_sizes, int n_in,
                              void* d_out, int out_size, void* d_ws, size_t ws_size,
                              hipStream_t stream) {
  const float* key    = (const float*)d_in[0];
  const float* value  = (const float*)d_in[1];
  const int*   labels = (const int*)d_in[2];
  const int*   lens   = (const int*)d_in[3];
  const float* emb    = (const float*)d_in[4];
  const float* w_ih0  = (const float*)d_in[5];
  const float* w_hh0  = (const float*)d_in[6];
  const float* b_ih0  = (const float*)d_in[7];
  const float* b_hh0  = (const float*)d_in[8];
  const float* w_ihr  = (const float*)d_in[9];
  const float* w_hhr  = (const float*)d_in[10];
  const float* b_ihr  = (const float*)d_in[11];
  const float* b_hhr  = (const float*)d_in[12];
  const float* fc1_w  = (const float*)d_in[13];
  const float* fc1_b  = (const float*)d_in[14];
  const float* fc2_w  = (const float*)d_in[15];
  const float* fc2_b  = (const float*)d_in[16];
  float* out = (float*)d_out;

  if (ws_size >= P_END) {
    char* base = (char*)d_ws;
    h2v* xeh    = (h2v*)(base + P_XEH);
    h2v* kf     = (h2v*)(base + P_KF);
    h2v* vf     = (h2v*)(base + P_VF);
    h2v* wih0t  = (h2v*)(base + P_WIH0);
    h2v* whh0t  = (h2v*)(base + P_WHH0);
    h2v* wir1t  = (h2v*)(base + P_WIR1);
    h2v* whh1t  = (h2v*)(base + P_WHH1);
    h2v* wir2t  = (h2v*)(base + P_WIR2);
    h2v* whh2t  = (h2v*)(base + P_WHH2);
    h2v* fc1t   = (h2v*)(base + P_FC1T);
    h2v* fc2h   = (h2v*)(base + P_FC2H);
    float* bsum = (float*)(base + P_BSUM);

    k_prep<<<10541 + 12, 256, 0, stream>>>(labels, emb, w_ih0, w_hh0, b_ih0, b_hh0,
                                           w_ihr, w_hhr, b_ihr, b_hhr, fc1_w, fc2_w,
                                           xeh, wih0t, whh0t, wir1t, whh1t, wir2t, whh2t,
                                           fc1t, fc2h, bsum);
    k_cvtKV<<<8192, 256, 0, stream>>>((const float2*)key, (const float2*)value,
                                      kf, vf, (int)((size_t)B * T * 128));
    k_seq<<<B, 1024, 0, stream>>>(xeh, kf, vf, lens,
                                  wih0t, whh0t, wir1t, whh1t, wir2t, whh2t, bsum,
                                  fc1t, fc1_b, fc2h, fc2_b, out);
  } else {
    float* ws = (float*)d_ws;
    k_init<<<(3 * HB + 255) / 256, 256, 0, stream>>>(ws);
    k_embed<<<(L * E * B + 255) / 256, 256, 0, stream>>>(labels, emb, ws + OFF_XE);
    launch_legacy(key, value, lens, w_ih0, w_hh0, b_ih0, b_hh0,
                  w_ihr, w_hhr, b_ihr, b_hhr, fc1_w, fc1_b, fc2_w, fc2_b,
                  out, ws, stream);
  }
}